// Round 13
// baseline (219.745 us; speedup 1.0000x reference)
//
#include <hip/hip_runtime.h>
#include <hip/hip_bf16.h>
#include <cstdint>
#include <cstddef>

// ---------------------------------------------------------------------------
// LocalAttention: B=4, S=2048, D=1024, WINDOW=10 (|i-j| <= 5)
// Double fold:
//   scores: Q_i.K_j = x_i.z_j + r2_i + r1_j + c,  z = x @ Bwy^T,
//     Bwy = Wqt @ Wkt^T ; w1 = bq@Wk, w2 = bk@Wq, c = bq.bk
//   out = attn @ Vp + bo, Vp = x @ Wp^T + bvo, Wp = Wo@Wv, bvo = Wo@bv
// Pipeline (4 launches):
//   prep2 (cvt + transpose3 + bvo + w1/w2 chunk-partials + c + cnt-zero)
//   splitk_r12 (Bwy/Wp split-K partials + last-block finisher -> W2 ; r12)
//   gemm_yv ([z|Vp] = xh @ W2^T + [0|bvo], m97 128^2)
//   attn_band (attn rows + out)
// d_out: out [4,2048,1024] f32, attn [4,2048,2048] f32 (concatenated)
// ---------------------------------------------------------------------------

typedef __attribute__((ext_vector_type(8))) short bf16x8;
typedef __attribute__((ext_vector_type(4))) float f32x4;
typedef __attribute__((ext_vector_type(8))) unsigned short ushortx8;

#define GPTR(x) ((const __attribute__((address_space(1))) void*)(x))
#define LPTR(x) ((__attribute__((address_space(3))) void*)(x))

__device__ __forceinline__ unsigned short f2bf(float f) {
    __hip_bfloat16 h = __float2bfloat16(f);
    unsigned short u;
    __builtin_memcpy(&u, &h, 2);
    return u;
}
__device__ __forceinline__ float bf2f(unsigned short u) {
    unsigned int x = ((unsigned int)u) << 16;
    float f;
    __builtin_memcpy(&f, &x, 4);
    return f;
}

// ------------------- prep2: cvt | transpose3 | bvo | wpart | c + cnt-zero ---
// blocks [0,9216): cvt ; [9216,9984): transpose ; [9984,10240): bvo ;
// [10240,10304): wpart ; [10304]: c + zero counters.
__global__ void prep2(const float* __restrict__ x,  const float* __restrict__ Wq,
                      const float* __restrict__ Wk, const float* __restrict__ Wv,
                      const float* __restrict__ Wo, const float* __restrict__ bv,
                      const float* __restrict__ bq, const float* __restrict__ bk,
                      unsigned short* __restrict__ xh,
                      unsigned short* __restrict__ Woh,
                      unsigned short* __restrict__ Wqt,
                      unsigned short* __restrict__ Wkt,
                      unsigned short* __restrict__ Wvt,
                      float* __restrict__ bvo,
                      float* __restrict__ wpart,
                      float* __restrict__ cbuf,
                      int* __restrict__ cnt) {
    __shared__ float tl[64][65];
    const int bid = blockIdx.x;
    if (bid < 9216) {
        const int idx = bid * 256 + threadIdx.x;     // f32x4 units
        const float* src;
        unsigned short* dst;
        int off;
        if (idx < 2097152) { src = x;  dst = xh;  off = idx; }
        else               { src = Wo; dst = Woh; off = idx - 2097152; }
        f32x4 v = reinterpret_cast<const f32x4*>(src)[off];
        ushort4 o;
        o.x = f2bf(v[0]); o.y = f2bf(v[1]); o.z = f2bf(v[2]); o.w = f2bf(v[3]);
        reinterpret_cast<ushort4*>(dst)[off] = o;
    } else if (bid < 9984) {
        const int u   = bid - 9216;                  // 0..767
        const int z   = u >> 8;
        const int rem = u & 255;
        const int by  = rem >> 4;
        const int bx  = rem & 15;
        const float* in = (z == 0) ? Wq : (z == 1) ? Wk : Wv;
        unsigned short* out = (z == 0) ? Wqt : (z == 1) ? Wkt : Wvt;
        const int t  = threadIdx.x;
        const int c  = t & 63;
        const int r4 = t >> 6;
#pragma unroll
        for (int i = 0; i < 16; ++i) {
            const int r = r4 * 16 + i;
            tl[r][c] = in[(size_t)(by * 64 + r) * 1024 + bx * 64 + c];
        }
        __syncthreads();
#pragma unroll
        for (int i = 0; i < 16; ++i) {
            const int r = r4 * 16 + i;
            out[(size_t)(bx * 64 + r) * 1024 + by * 64 + c] = f2bf(tl[c][r]);
        }
    } else if (bid < 10240) {
        const int row  = (bid - 9984) * 4 + (threadIdx.x >> 6);
        const int lane = threadIdx.x & 63;
        float s = 0.f;
#pragma unroll
        for (int k = lane; k < 1024; k += 64)
            s += Wo[(size_t)row * 1024 + k] * bv[k];
#pragma unroll
        for (int off = 32; off >= 1; off >>= 1) s += __shfl_xor(s, off, 64);
        if (lane == 0) bvo[row] = s;
    } else if (bid < 10304) {
        // wpart[mat][chunk][d]: mat0 = w1 partial (bq@Wk), mat1 = w2 (bk@Wq)
        const int u     = bid - 10240;               // 0..63
        const int mat   = u >> 5;
        const int rest  = u & 31;
        const int chunk = rest >> 2;                 // 0..7 (n-range of 128)
        const int dg    = rest & 3;                  // 0..3 (d-group of 256)
        const int d     = dg * 256 + threadIdx.x;
        const float* W  = mat ? Wq : Wk;
        const float* bs = mat ? bk : bq;
        float acc = 0.f;
        const int n0 = chunk * 128;
        for (int n = n0; n < n0 + 128; ++n)
            acc += bs[n] * W[(size_t)n * 1024 + d];
        wpart[(size_t)(mat * 8 + chunk) * 1024 + d] = acc;
    } else {
        // c = bq.bk ; zero split-K finisher counters
        if (threadIdx.x < 128) cnt[threadIdx.x] = 0;
        __shared__ float red[256];
        float pc = 0.f;
        for (int n = threadIdx.x; n < 1024; n += 256) pc += bq[n] * bk[n];
        red[threadIdx.x] = pc;
        __syncthreads();
        for (int s = 128; s > 0; s >>= 1) {
            if (threadIdx.x < s) red[threadIdx.x] += red[threadIdx.x + s];
            __syncthreads();
        }
        if (threadIdx.x == 0) cbuf[0] = red[0];
    }
}

// ------------------- GEMM core: 128x128 tile, BK=64, 4 waves (m97) ---------
__device__ __forceinline__ void gemm_core(const unsigned short* __restrict__ A,
                                          const unsigned short* __restrict__ Bw,
                                          int Kstride, int nk, int tm, int tn,
                                          unsigned short* As, unsigned short* Bs,
                                          f32x4 (&acc)[4][4]) {
    const int tid  = threadIdx.x;
    const int lane = tid & 63;
    const int w    = tid >> 6;
    const int wr   = w >> 1;
    const int wc   = w & 1;

    const int lrow8 = lane >> 3;
    const int lcolb = (lane & 7) << 4;

    const char* Abase = (const char*)(A + (size_t)tm * 128 * (size_t)Kstride);
    const char* Bbase = (const char*)(Bw + (size_t)tn * 128 * (size_t)Kstride);
    const size_t rstride = (size_t)Kstride * 2;

    for (int t = 0; t < nk; ++t) {
        const size_t k0b = ((size_t)t << 6) * 2;
#pragma unroll
        for (int ii = 0; ii < 4; ++ii) {
            const int c    = (w << 2) + ii;
            const int row  = (c << 3) + lrow8;
            const int csrc = lcolb ^ ((row & 7) << 4);
            __builtin_amdgcn_global_load_lds(
                GPTR(Abase + (size_t)row * rstride + k0b + (size_t)csrc),
                LPTR((char*)As + (c << 10)), 16, 0, 0);
            __builtin_amdgcn_global_load_lds(
                GPTR(Bbase + (size_t)row * rstride + k0b + (size_t)csrc),
                LPTR((char*)Bs + (c << 10)), 16, 0, 0);
        }
        __syncthreads();

#pragma unroll
        for (int kk = 0; kk < 2; ++kk) {
            bf16x8 af[4], bfr[4];
            const int cb = (kk << 6) + ((lane >> 4) << 4);
#pragma unroll
            for (int m = 0; m < 4; ++m) {
                const int row = (wr << 6) + (m << 4) + (lane & 15);
                af[m] = *reinterpret_cast<const bf16x8*>(
                    (const char*)As + row * 128 + (cb ^ ((row & 7) << 4)));
            }
#pragma unroll
            for (int n = 0; n < 4; ++n) {
                const int row = (wc << 6) + (n << 4) + (lane & 15);
                bfr[n] = *reinterpret_cast<const bf16x8*>(
                    (const char*)Bs + row * 128 + (cb ^ ((row & 7) << 4)));
            }
#pragma unroll
            for (int m = 0; m < 4; ++m)
#pragma unroll
                for (int n = 0; n < 4; ++n)
                    acc[m][n] = __builtin_amdgcn_mfma_f32_16x16x32_bf16(
                        af[m], bfr[n], acc[m][n], 0, 0, 0);
        }
        __syncthreads();
    }
}

// ------------------- splitk (+ last-block finisher -> W2) | r12 -------------
// blocks [0,512): split-K partials + finisher; [512,2560): r12 rows.
__launch_bounds__(256, 3)
__global__ void splitk_r12(const unsigned short* __restrict__ Wqt,
                           const unsigned short* __restrict__ Wkt,
                           const unsigned short* __restrict__ Woh,
                           const unsigned short* __restrict__ Wvt,
                           float* __restrict__ part,
                           unsigned short* __restrict__ W2,
                           int* __restrict__ cnt,
                           const unsigned short* __restrict__ xh,
                           const float* __restrict__ wpart,
                           const float* __restrict__ cbuf,
                           float* __restrict__ r1, float* __restrict__ r2) {
    __shared__ unsigned short As[128 * 64];
    __shared__ unsigned short Bs[128 * 64];
    const int bid = blockIdx.x;
    if (bid >= 512) {
        // ---- r12: reconstruct w1/w2 from wpart, then r1/r2 ----
        const int w    = threadIdx.x >> 6;
        const int lane = threadIdx.x & 63;
        const int g    = (bid - 512) * 4 + w;
        const f32x4* wp4 = reinterpret_cast<const f32x4*>(wpart);
        f32x4 w1x[4], w2x[4];
#pragma unroll
        for (int q = 0; q < 4; ++q) {
            w1x[q] = (f32x4){0.f, 0.f, 0.f, 0.f};
            w2x[q] = (f32x4){0.f, 0.f, 0.f, 0.f};
        }
#pragma unroll
        for (int c = 0; c < 8; ++c)
#pragma unroll
            for (int q = 0; q < 4; ++q) {
                w1x[q] += wp4[(c << 8) + (lane << 2) + q];
                w2x[q] += wp4[2048 + (c << 8) + (lane << 2) + q];
            }
        const unsigned short* row = xh + (size_t)g * 1024 + (lane << 4);
        ushortx8 xa = *reinterpret_cast<const ushortx8*>(row);
        ushortx8 xb = *reinterpret_cast<const ushortx8*>(row + 8);
        float a1 = 0.f, a2 = 0.f;
#pragma unroll
        for (int t = 0; t < 8; ++t) {
            const float xv = bf2f(xa[t]);
            const float xw = bf2f(xb[t]);
            a1 += xv * w1x[t >> 2][t & 3] + xw * w1x[2 + (t >> 2)][t & 3];
            a2 += xv * w2x[t >> 2][t & 3] + xw * w2x[2 + (t >> 2)][t & 3];
        }
#pragma unroll
        for (int off = 32; off >= 1; off >>= 1) {
            a1 += __shfl_xor(a1, off, 64);
            a2 += __shfl_xor(a2, off, 64);
        }
        if (lane == 0) { r1[g] = a1 + cbuf[0]; r2[g] = a2; }
        return;
    }

    f32x4 acc[4][4];
#pragma unroll
    for (int m = 0; m < 4; ++m)
#pragma unroll
        for (int n = 0; n < 4; ++n) acc[m][n] = (f32x4){0.f, 0.f, 0.f, 0.f};

    const int mat = bid >> 8;          // 0: Bwy = Wqt@Wkt^T, 1: Wp = Woh@Wvt^T
    const int loc = bid & 255;
    const int ks  = loc >> 6;          // 0..3 -> K offset ks*256
    const int t64 = loc & 63;
    const int tm  = t64 >> 3;
    const int tn  = t64 & 7;

    const unsigned short* A = mat ? Woh : Wqt;
    const unsigned short* B = mat ? Wvt : Wkt;
    gemm_core(A + ks * 256, B + ks * 256, 1024, 4, tm, tn, As, Bs, acc);

    float* dst = part + ((size_t)(mat * 4 + ks) << 20);
    const int lane = threadIdx.x & 63;
    const int w    = threadIdx.x >> 6;
    const int wr   = w >> 1, wc = w & 1;
    const int col0 = (tn << 7) + (wc << 6) + (lane & 15);
    const int row0 = (tm << 7) + (wr << 6) + ((lane >> 4) << 2);
#pragma unroll
    for (int n = 0; n < 4; ++n) {
        const int col = col0 + (n << 4);
#pragma unroll
        for (int m = 0; m < 4; ++m) {
            const int row = row0 + (m << 4);
#pragma unroll
            for (int r = 0; r < 4; ++r)
                dst[(size_t)(row + r) * 1024 + col] = acc[m][n][r];
        }
    }

    // ---- last-block finisher: reduce 4 partials of this tile -> bf16 W2 ----
    __shared__ int lastFlag;
    __threadfence();                         // release own partial stores
    __syncthreads();                         // all threads fenced
    if (threadIdx.x == 0)
        lastFlag = (atomicAdd(&cnt[mat * 64 + t64], 1) == 3);
    __syncthreads();
    if (lastFlag) {
        __threadfence();                     // acquire other blocks' partials
        const size_t pbase = (size_t)(mat * 4) << 20;
        for (int u = threadIdx.x; u < 4096; u += 256) {
            const int rl = u >> 5;           // 0..127 tile row
            const int cu = u & 31;           // f32x4 col unit
            const size_t eoff = (size_t)(tm * 128 + rl) * 1024 + tn * 128 + cu * 4;
            f32x4 s = *reinterpret_cast<const f32x4*>(part + pbase + eoff);
            s += *reinterpret_cast<const f32x4*>(part + pbase + (1u << 20) + eoff);
            s += *reinterpret_cast<const f32x4*>(part + pbase + (2u << 20) + eoff);
            s += *reinterpret_cast<const f32x4*>(part + pbase + (3u << 20) + eoff);
            ushort4 o;
            o.x = f2bf(s[0]); o.y = f2bf(s[1]); o.z = f2bf(s[2]); o.w = f2bf(s[3]);
            *reinterpret_cast<ushort4*>(
                W2 + (size_t)(mat * 1024 + tm * 128 + rl) * 1024 + tn * 128 + cu * 4) = o;
        }
    }
}

// ------------------- [z | Vp] = xh @ W2^T + [0 | bvo] -> bf16 [8192,2048] ---
__launch_bounds__(256, 4)
__global__ void gemm_yv(const unsigned short* __restrict__ A,
                        const unsigned short* __restrict__ Bw,
                        const float* __restrict__ bvo,
                        unsigned short* __restrict__ C) {
    __shared__ unsigned short As[128 * 64];
    __shared__ unsigned short Bs[128 * 64];
    f32x4 acc[4][4];
#pragma unroll
    for (int m = 0; m < 4; ++m)
#pragma unroll
        for (int n = 0; n < 4; ++n) acc[m][n] = (f32x4){0.f, 0.f, 0.f, 0.f};

    const int sid = (blockIdx.x & 7) * (gridDim.x >> 3) + (blockIdx.x >> 3);
    const int tm  = sid >> 4;
    const int tn  = sid & 15;

    gemm_core(A, Bw, 1024, 16, tm, tn, As, Bs, acc);

    const int lane = threadIdx.x & 63;
    const int w    = threadIdx.x >> 6;
    const int wr   = w >> 1, wc = w & 1;
    const int seg  = tn >> 3;            // 0: z (no bias), 1: Vp (+bvo)
    const int col0 = (tn << 7) + (wc << 6) + (lane & 15);
    const int row0 = (tm << 7) + (wr << 6) + ((lane >> 4) << 2);
#pragma unroll
    for (int n = 0; n < 4; ++n) {
        const int col = col0 + (n << 4);
        const float bb = seg ? bvo[col & 1023] : 0.f;
#pragma unroll
        for (int m = 0; m < 4; ++m) {
            const int row = row0 + (m << 4);
#pragma unroll
            for (int r = 0; r < 4; ++r)
                C[(size_t)(row + r) * 2048 + col] = f2bf(acc[m][n][r] + bb);
        }
    }
}

// ------------------- band attention: attn rows + final out ------------------
__launch_bounds__(256, 4)
__global__ void attn_band_kernel(const unsigned short* __restrict__ xh,
                                 const unsigned short* __restrict__ yVp,
                                 const float* __restrict__ r1,
                                 const float* __restrict__ r2,
                                 const float* __restrict__ bo,
                                 float* __restrict__ attn,
                                 float* __restrict__ outp) {
    __shared__ float psm[4][16];
    const int bid  = blockIdx.x;
    const int rb   = (bid & 7) * 256 + (bid >> 3);   // XCD-contiguous swizzle
    const int w    = threadIdx.x >> 6;
    const int lane = threadIdx.x & 63;
    const int g    = (rb << 2) + w;                  // row 0..8191
    const int b    = g >> 11;
    const int i    = g & 2047;

    const unsigned short* qrow = xh + (size_t)g * 1024;
    float qf[16];
    {
        ushortx8 qa = *reinterpret_cast<const ushortx8*>(qrow + (lane << 4));
        ushortx8 qb = *reinterpret_cast<const ushortx8*>(qrow + (lane << 4) + 8);
#pragma unroll
        for (int t = 0; t < 8; ++t) { qf[t] = bf2f(qa[t]); qf[8 + t] = bf2f(qb[t]); }
    }
    const float r2g = r2[g];

    float s[11];
#pragma unroll
    for (int jj = 0; jj < 11; ++jj) {
        const int j = i - 5 + jj;
        const bool valid = ((unsigned)j < 2048u);
        const int jc = min(max(j, 0), 2047);
        const int gj = (b << 11) + jc;
        const unsigned short* krow = yVp + (size_t)gj * 2048;
        ushortx8 ka = *reinterpret_cast<const ushortx8*>(krow + (lane << 4));
        ushortx8 kb = *reinterpret_cast<const ushortx8*>(krow + (lane << 4) + 8);
        float d = 0.f;
#pragma unroll
        for (int t = 0; t < 8; ++t)
            d += qf[t] * bf2f(ka[t]) + qf[8 + t] * bf2f(kb[t]);
#pragma unroll
        for (int off = 32; off >= 1; off >>= 1) d += __shfl_xor(d, off, 64);
        s[jj] = valid ? (d + r2g + r1[gj]) * 0.03125f : -1e30f;
    }

    float mx = s[0];
#pragma unroll
    for (int jj = 1; jj < 11; ++jj) mx = fmaxf(mx, s[jj]);
    float p[11], sum = 0.f;
#pragma unroll
    for (int jj = 0; jj < 11; ++jj) { p[jj] = expf(s[jj] - mx); sum += p[jj]; }
    const float inv = 1.0f / sum;

    if (lane == 0) {
#pragma unroll
        for (int jj = 0; jj < 11; ++jj) psm[w][jj] = p[jj] * inv;
    }
    __syncthreads();

    const int lo = i - 5;
    float* arow = attn + (size_t)g * 2048;
#pragma unroll
    for (int e = 0; e < 8; ++e) {
        const int c0 = (e << 8) + (lane << 2);
        f32x4 v = (f32x4){0.f, 0.f, 0.f, 0.f};
        if (c0 + 3 >= lo && c0 <= lo + 10) {
#pragma unroll
            for (int t = 0; t < 4; ++t) {
                const int d = c0 + t - lo;
                if ((unsigned)d < 11u) v[t] = psm[w][d];
            }
        }
        *reinterpret_cast<f32x4*>(arow + c0) = v;
    }

    float cacc[16];
#pragma unroll
    for (int t = 0; t < 16; ++t) cacc[t] = 0.f;
#pragma unroll
    for (int jj = 0; jj < 11; ++jj) {
        const int j  = i - 5 + jj;
        const int jc = min(max(j, 0), 2047);
        const float pj = p[jj] * inv;
        const unsigned short* vrow = yVp + ((size_t)((b << 11) + jc)) * 2048 + 1024;
        ushortx8 va = *reinterpret_cast<const ushortx8*>(vrow + (lane << 4));
        ushortx8 vb = *reinterpret_cast<const ushortx8*>(vrow + (lane << 4) + 8);
#pragma unroll
        for (int t = 0; t < 8; ++t) {
            cacc[t]     += pj * bf2f(va[t]);
            cacc[8 + t] += pj * bf2f(vb[t]);
        }
    }
    const int c0 = lane << 4;
    float* op = outp + (size_t)g * 1024 + c0;
#pragma unroll
    for (int q = 0; q < 4; ++q) {
        f32x4 bb = *reinterpret_cast<const f32x4*>(bo + c0 + (q << 2));
        f32x4 o;
#pragma unroll
        for (int t = 0; t < 4; ++t) o[t] = cacc[(q << 2) + t] + bb[t];
        *reinterpret_cast<f32x4*>(op + (q << 2)) = o;
    }
}

// ------------------------------ launch --------------------------------------
extern "C" void kernel_launch(void* const* d_in, const int* in_sizes, int n_in,
                              void* d_out, int out_size, void* d_ws, size_t ws_size,
                              hipStream_t stream) {
    const float* x  = (const float*)d_in[0];
    const float* Wq = (const float*)d_in[1];
    const float* bq = (const float*)d_in[2];
    const float* Wk = (const float*)d_in[3];
    const float* bk = (const float*)d_in[4];
    const float* Wv = (const float*)d_in[5];
    const float* bv = (const float*)d_in[6];
    const float* Wo = (const float*)d_in[7];
    const float* bo = (const float*)d_in[8];

    const size_t MS = 8192, DD = 1024;

    float* out  = (float*)d_out;              // [8192,1024] f32
    float* attn = out + MS * DD;              // [4,2048,2048] f32

    char* ws = (char*)d_ws;
    unsigned short* xh   = (unsigned short*)ws; ws += MS * DD * 2;
    unsigned short* Woh  = (unsigned short*)ws; ws += DD * DD * 2;
    unsigned short* Wqt  = (unsigned short*)ws; ws += DD * DD * 2;
    unsigned short* Wkt  = (unsigned short*)ws; ws += DD * DD * 2;
    unsigned short* Wvt  = (unsigned short*)ws; ws += DD * DD * 2;
    float*          bvo  = (float*)ws;          ws += DD * 4;
    float*          wpart= (float*)ws;          ws += 16 * DD * 4;   // [2][8][1024]
    float*          cbuf = (float*)ws;          ws += 256;
    int*            cnt  = (int*)ws;            ws += 512;           // 128 counters
    float*          r1   = (float*)ws;          ws += MS * 4;
    float*          r2   = (float*)ws;          ws += MS * 4;
    float*          part = (float*)ws;          ws += (size_t)8 * DD * DD * 4;
    unsigned short* W2   = (unsigned short*)ws; ws += 2 * DD * DD * 2;
    unsigned short* yVp  = (unsigned short*)ws; ws += MS * 2 * DD * 2;

    // 1) prep: cvt + transpose3 + bvo + w1/w2 partials + c + counter-zero
    prep2<<<dim3(10305), dim3(256), 0, stream>>>(x, Wq, Wk, Wv, Wo, bv, bq, bk,
                                                 xh, Woh, Wqt, Wkt, Wvt, bvo,
                                                 wpart, cbuf, cnt);

    // 2) split-K weight GEMMs (+finisher -> W2) and r12
    splitk_r12<<<dim3(2560), dim3(256), 0, stream>>>(Wqt, Wkt, Woh, Wvt, part,
                                                     W2, cnt, xh, wpart, cbuf,
                                                     r1, r2);

    // 3) [z | Vp] = xh @ W2^T + [0 | bvo]
    gemm_yv<<<dim3(1024), dim3(256), 0, stream>>>(xh, W2, bvo, yVp);

    // 4) band attention: attn rows + final out -> d_out
    attn_band_kernel<<<dim3(2048), dim3(256), 0, stream>>>(xh, yVp, r1, r2, bo,
                                                           attn, out);
}

// Round 14
// 139.150 us; speedup vs baseline: 1.5792x; 1.5792x over previous
//
#include <hip/hip_runtime.h>
#include <hip/hip_bf16.h>
#include <cstdint>
#include <cstddef>

// ---------------------------------------------------------------------------
// LocalAttention: B=4, S=2048, D=1024, WINDOW=10 (|i-j| <= 5)
// Double fold:
//   scores: Q_i.K_j = x_i.z_j + r2_i + r1_j + c,  z = x @ Bwy^T,
//     Bwy = Wqt @ Wkt^T ; w1 = bq@Wk, w2 = bk@Wq, c = bq.bk
//   out = attn @ Vp + bo, Vp = x @ Wp^T + bvo, Wp = Wo@Wv, bvo = Wo@bv
// Pipeline (5 launches):
//   prep2 (cvt + transpose3 + bvo + w1/w2 chunk-partials + c)
//   splitk_r12 (Bwy/Wp split-K partials ; r12 from wpart)   [no fences]
//   reduce_wp (partials -> bf16 W2)
//   gemm_yv ([z|Vp] = xh @ W2^T + [0|bvo], m97 128^2)
//   attn_band (attn rows + out)
// d_out: out [4,2048,1024] f32, attn [4,2048,2048] f32 (concatenated)
// ---------------------------------------------------------------------------

typedef __attribute__((ext_vector_type(8))) short bf16x8;
typedef __attribute__((ext_vector_type(4))) float f32x4;
typedef __attribute__((ext_vector_type(8))) unsigned short ushortx8;

#define GPTR(x) ((const __attribute__((address_space(1))) void*)(x))
#define LPTR(x) ((__attribute__((address_space(3))) void*)(x))

__device__ __forceinline__ unsigned short f2bf(float f) {
    __hip_bfloat16 h = __float2bfloat16(f);
    unsigned short u;
    __builtin_memcpy(&u, &h, 2);
    return u;
}
__device__ __forceinline__ float bf2f(unsigned short u) {
    unsigned int x = ((unsigned int)u) << 16;
    float f;
    __builtin_memcpy(&f, &x, 4);
    return f;
}

// ------------------- prep2: cvt | transpose3 | bvo | wpart | c --------------
// blocks [0,9216): cvt ; [9216,9984): transpose ; [9984,10240): bvo ;
// [10240,10304): wpart ; [10304]: c.
__global__ void prep2(const float* __restrict__ x,  const float* __restrict__ Wq,
                      const float* __restrict__ Wk, const float* __restrict__ Wv,
                      const float* __restrict__ Wo, const float* __restrict__ bv,
                      const float* __restrict__ bq, const float* __restrict__ bk,
                      unsigned short* __restrict__ xh,
                      unsigned short* __restrict__ Woh,
                      unsigned short* __restrict__ Wqt,
                      unsigned short* __restrict__ Wkt,
                      unsigned short* __restrict__ Wvt,
                      float* __restrict__ bvo,
                      float* __restrict__ wpart,
                      float* __restrict__ cbuf) {
    __shared__ float tl[64][65];
    const int bid = blockIdx.x;
    if (bid < 9216) {
        const int idx = bid * 256 + threadIdx.x;     // f32x4 units
        const float* src;
        unsigned short* dst;
        int off;
        if (idx < 2097152) { src = x;  dst = xh;  off = idx; }
        else               { src = Wo; dst = Woh; off = idx - 2097152; }
        f32x4 v = reinterpret_cast<const f32x4*>(src)[off];
        ushort4 o;
        o.x = f2bf(v[0]); o.y = f2bf(v[1]); o.z = f2bf(v[2]); o.w = f2bf(v[3]);
        reinterpret_cast<ushort4*>(dst)[off] = o;
    } else if (bid < 9984) {
        const int u   = bid - 9216;                  // 0..767
        const int z   = u >> 8;
        const int rem = u & 255;
        const int by  = rem >> 4;
        const int bx  = rem & 15;
        const float* in = (z == 0) ? Wq : (z == 1) ? Wk : Wv;
        unsigned short* out = (z == 0) ? Wqt : (z == 1) ? Wkt : Wvt;
        const int t  = threadIdx.x;
        const int c  = t & 63;
        const int r4 = t >> 6;
#pragma unroll
        for (int i = 0; i < 16; ++i) {
            const int r = r4 * 16 + i;
            tl[r][c] = in[(size_t)(by * 64 + r) * 1024 + bx * 64 + c];
        }
        __syncthreads();
#pragma unroll
        for (int i = 0; i < 16; ++i) {
            const int r = r4 * 16 + i;
            out[(size_t)(bx * 64 + r) * 1024 + by * 64 + c] = f2bf(tl[c][r]);
        }
    } else if (bid < 10240) {
        const int row  = (bid - 9984) * 4 + (threadIdx.x >> 6);
        const int lane = threadIdx.x & 63;
        float s = 0.f;
#pragma unroll
        for (int k = lane; k < 1024; k += 64)
            s += Wo[(size_t)row * 1024 + k] * bv[k];
#pragma unroll
        for (int off = 32; off >= 1; off >>= 1) s += __shfl_xor(s, off, 64);
        if (lane == 0) bvo[row] = s;
    } else if (bid < 10304) {
        // wpart[mat][chunk][d]: mat0 = w1 partial (bq@Wk), mat1 = w2 (bk@Wq)
        const int u     = bid - 10240;               // 0..63
        const int mat   = u >> 5;
        const int rest  = u & 31;
        const int chunk = rest >> 2;                 // 0..7 (n-range of 128)
        const int dg    = rest & 3;                  // 0..3 (d-group of 256)
        const int d     = dg * 256 + threadIdx.x;
        const float* W  = mat ? Wq : Wk;
        const float* bs = mat ? bk : bq;
        float acc = 0.f;
        const int n0 = chunk * 128;
        for (int n = n0; n < n0 + 128; ++n)
            acc += bs[n] * W[(size_t)n * 1024 + d];
        wpart[(size_t)(mat * 8 + chunk) * 1024 + d] = acc;
    } else {
        // c = bq.bk
        __shared__ float red[256];
        float pc = 0.f;
        for (int n = threadIdx.x; n < 1024; n += 256) pc += bq[n] * bk[n];
        red[threadIdx.x] = pc;
        __syncthreads();
        for (int s = 128; s > 0; s >>= 1) {
            if (threadIdx.x < s) red[threadIdx.x] += red[threadIdx.x + s];
            __syncthreads();
        }
        if (threadIdx.x == 0) cbuf[0] = red[0];
    }
}

// ------------------- GEMM core: 128x128 tile, BK=64, 4 waves (m97) ---------
__device__ __forceinline__ void gemm_core(const unsigned short* __restrict__ A,
                                          const unsigned short* __restrict__ Bw,
                                          int Kstride, int nk, int tm, int tn,
                                          unsigned short* As, unsigned short* Bs,
                                          f32x4 (&acc)[4][4]) {
    const int tid  = threadIdx.x;
    const int lane = tid & 63;
    const int w    = tid >> 6;
    const int wr   = w >> 1;
    const int wc   = w & 1;

    const int lrow8 = lane >> 3;
    const int lcolb = (lane & 7) << 4;

    const char* Abase = (const char*)(A + (size_t)tm * 128 * (size_t)Kstride);
    const char* Bbase = (const char*)(Bw + (size_t)tn * 128 * (size_t)Kstride);
    const size_t rstride = (size_t)Kstride * 2;

    for (int t = 0; t < nk; ++t) {
        const size_t k0b = ((size_t)t << 6) * 2;
#pragma unroll
        for (int ii = 0; ii < 4; ++ii) {
            const int c    = (w << 2) + ii;
            const int row  = (c << 3) + lrow8;
            const int csrc = lcolb ^ ((row & 7) << 4);
            __builtin_amdgcn_global_load_lds(
                GPTR(Abase + (size_t)row * rstride + k0b + (size_t)csrc),
                LPTR((char*)As + (c << 10)), 16, 0, 0);
            __builtin_amdgcn_global_load_lds(
                GPTR(Bbase + (size_t)row * rstride + k0b + (size_t)csrc),
                LPTR((char*)Bs + (c << 10)), 16, 0, 0);
        }
        __syncthreads();

#pragma unroll
        for (int kk = 0; kk < 2; ++kk) {
            bf16x8 af[4], bfr[4];
            const int cb = (kk << 6) + ((lane >> 4) << 4);
#pragma unroll
            for (int m = 0; m < 4; ++m) {
                const int row = (wr << 6) + (m << 4) + (lane & 15);
                af[m] = *reinterpret_cast<const bf16x8*>(
                    (const char*)As + row * 128 + (cb ^ ((row & 7) << 4)));
            }
#pragma unroll
            for (int n = 0; n < 4; ++n) {
                const int row = (wc << 6) + (n << 4) + (lane & 15);
                bfr[n] = *reinterpret_cast<const bf16x8*>(
                    (const char*)Bs + row * 128 + (cb ^ ((row & 7) << 4)));
            }
#pragma unroll
            for (int m = 0; m < 4; ++m)
#pragma unroll
                for (int n = 0; n < 4; ++n)
                    acc[m][n] = __builtin_amdgcn_mfma_f32_16x16x32_bf16(
                        af[m], bfr[n], acc[m][n], 0, 0, 0);
        }
        __syncthreads();
    }
}

// ------------------- splitk (Bwy, Wp partials) | r12 (from wpart) -----------
// blocks [0,512): split-K GEMM partials; [512,2560): r12 rows. NO fences.
__launch_bounds__(256, 3)
__global__ void splitk_r12(const unsigned short* __restrict__ Wqt,
                           const unsigned short* __restrict__ Wkt,
                           const unsigned short* __restrict__ Woh,
                           const unsigned short* __restrict__ Wvt,
                           float* __restrict__ part,
                           const unsigned short* __restrict__ xh,
                           const float* __restrict__ wpart,
                           const float* __restrict__ cbuf,
                           float* __restrict__ r1, float* __restrict__ r2) {
    __shared__ unsigned short As[128 * 64];
    __shared__ unsigned short Bs[128 * 64];
    const int bid = blockIdx.x;
    if (bid >= 512) {
        // ---- r12: reconstruct w1/w2 from wpart (L2-hot), then r1/r2 ----
        const int w    = threadIdx.x >> 6;
        const int lane = threadIdx.x & 63;
        const int g    = (bid - 512) * 4 + w;
        const f32x4* wp4 = reinterpret_cast<const f32x4*>(wpart);
        f32x4 w1x[4], w2x[4];
#pragma unroll
        for (int q = 0; q < 4; ++q) {
            w1x[q] = (f32x4){0.f, 0.f, 0.f, 0.f};
            w2x[q] = (f32x4){0.f, 0.f, 0.f, 0.f};
        }
#pragma unroll
        for (int c = 0; c < 8; ++c)
#pragma unroll
            for (int q = 0; q < 4; ++q) {
                w1x[q] += wp4[(c << 8) + (lane << 2) + q];
                w2x[q] += wp4[2048 + (c << 8) + (lane << 2) + q];
            }
        const unsigned short* row = xh + (size_t)g * 1024 + (lane << 4);
        ushortx8 xa = *reinterpret_cast<const ushortx8*>(row);
        ushortx8 xb = *reinterpret_cast<const ushortx8*>(row + 8);
        float a1 = 0.f, a2 = 0.f;
#pragma unroll
        for (int t = 0; t < 8; ++t) {
            const float xv = bf2f(xa[t]);
            const float xw = bf2f(xb[t]);
            a1 += xv * w1x[t >> 2][t & 3] + xw * w1x[2 + (t >> 2)][t & 3];
            a2 += xv * w2x[t >> 2][t & 3] + xw * w2x[2 + (t >> 2)][t & 3];
        }
#pragma unroll
        for (int off = 32; off >= 1; off >>= 1) {
            a1 += __shfl_xor(a1, off, 64);
            a2 += __shfl_xor(a2, off, 64);
        }
        if (lane == 0) { r1[g] = a1 + cbuf[0]; r2[g] = a2; }
        return;
    }

    f32x4 acc[4][4];
#pragma unroll
    for (int m = 0; m < 4; ++m)
#pragma unroll
        for (int n = 0; n < 4; ++n) acc[m][n] = (f32x4){0.f, 0.f, 0.f, 0.f};

    const int mat = bid >> 8;          // 0: Bwy = Wqt@Wkt^T, 1: Wp = Woh@Wvt^T
    const int loc = bid & 255;
    const int ks  = loc >> 6;          // 0..3 -> K offset ks*256
    const int t64 = loc & 63;
    const int tm  = t64 >> 3;
    const int tn  = t64 & 7;

    const unsigned short* A = mat ? Woh : Wqt;
    const unsigned short* B = mat ? Wvt : Wkt;
    gemm_core(A + ks * 256, B + ks * 256, 1024, 4, tm, tn, As, Bs, acc);

    float* dst = part + ((size_t)(mat * 4 + ks) << 20);
    const int lane = threadIdx.x & 63;
    const int w    = threadIdx.x >> 6;
    const int wr   = w >> 1, wc = w & 1;
    const int col0 = (tn << 7) + (wc << 6) + (lane & 15);
    const int row0 = (tm << 7) + (wr << 6) + ((lane >> 4) << 2);
#pragma unroll
    for (int n = 0; n < 4; ++n) {
        const int col = col0 + (n << 4);
#pragma unroll
        for (int m = 0; m < 4; ++m) {
            const int row = row0 + (m << 4);
#pragma unroll
            for (int r = 0; r < 4; ++r)
                dst[(size_t)(row + r) * 1024 + col] = acc[m][n][r];
        }
    }
}

// ------------------- reduce partials -> W2 = [Bwy; Wp] bf16 [2048][1024] ----
__global__ void reduce_wp(const float* __restrict__ part,
                          unsigned short* __restrict__ W2) {
    const int u = blockIdx.x * 256 + threadIdx.x;   // 0..524287 f32x4 units
    const int mat = u >> 18;
    const int off = u & 262143;
    const f32x4* p = reinterpret_cast<const f32x4*>(part);
    f32x4 s = p[((size_t)(mat * 4 + 0) << 18) + off];
    s += p[((size_t)(mat * 4 + 1) << 18) + off];
    s += p[((size_t)(mat * 4 + 2) << 18) + off];
    s += p[((size_t)(mat * 4 + 3) << 18) + off];
    ushort4 o;
    o.x = f2bf(s[0]); o.y = f2bf(s[1]); o.z = f2bf(s[2]); o.w = f2bf(s[3]);
    reinterpret_cast<ushort4*>(W2)[u] = o;
}

// ------------------- [z | Vp] = xh @ W2^T + [0 | bvo] -> bf16 [8192,2048] ---
__launch_bounds__(256, 4)
__global__ void gemm_yv(const unsigned short* __restrict__ A,
                        const unsigned short* __restrict__ Bw,
                        const float* __restrict__ bvo,
                        unsigned short* __restrict__ C) {
    __shared__ unsigned short As[128 * 64];
    __shared__ unsigned short Bs[128 * 64];
    f32x4 acc[4][4];
#pragma unroll
    for (int m = 0; m < 4; ++m)
#pragma unroll
        for (int n = 0; n < 4; ++n) acc[m][n] = (f32x4){0.f, 0.f, 0.f, 0.f};

    const int sid = (blockIdx.x & 7) * (gridDim.x >> 3) + (blockIdx.x >> 3);
    const int tm  = sid >> 4;
    const int tn  = sid & 15;

    gemm_core(A, Bw, 1024, 16, tm, tn, As, Bs, acc);

    const int lane = threadIdx.x & 63;
    const int w    = threadIdx.x >> 6;
    const int wr   = w >> 1, wc = w & 1;
    const int seg  = tn >> 3;            // 0: z (no bias), 1: Vp (+bvo)
    const int col0 = (tn << 7) + (wc << 6) + (lane & 15);
    const int row0 = (tm << 7) + (wr << 6) + ((lane >> 4) << 2);
#pragma unroll
    for (int n = 0; n < 4; ++n) {
        const int col = col0 + (n << 4);
        const float bb = seg ? bvo[col & 1023] : 0.f;
#pragma unroll
        for (int m = 0; m < 4; ++m) {
            const int row = row0 + (m << 4);
#pragma unroll
            for (int r = 0; r < 4; ++r)
                C[(size_t)(row + r) * 2048 + col] = f2bf(acc[m][n][r] + bb);
        }
    }
}

// ------------------- band attention: attn rows + final out ------------------
__launch_bounds__(256, 4)
__global__ void attn_band_kernel(const unsigned short* __restrict__ xh,
                                 const unsigned short* __restrict__ yVp,
                                 const float* __restrict__ r1,
                                 const float* __restrict__ r2,
                                 const float* __restrict__ bo,
                                 float* __restrict__ attn,
                                 float* __restrict__ outp) {
    __shared__ float psm[4][16];
    const int bid  = blockIdx.x;
    const int rb   = (bid & 7) * 256 + (bid >> 3);   // XCD-contiguous swizzle
    const int w    = threadIdx.x >> 6;
    const int lane = threadIdx.x & 63;
    const int g    = (rb << 2) + w;                  // row 0..8191
    const int b    = g >> 11;
    const int i    = g & 2047;

    const unsigned short* qrow = xh + (size_t)g * 1024;
    float qf[16];
    {
        ushortx8 qa = *reinterpret_cast<const ushortx8*>(qrow + (lane << 4));
        ushortx8 qb = *reinterpret_cast<const ushortx8*>(qrow + (lane << 4) + 8);
#pragma unroll
        for (int t = 0; t < 8; ++t) { qf[t] = bf2f(qa[t]); qf[8 + t] = bf2f(qb[t]); }
    }
    const float r2g = r2[g];

    float s[11];
#pragma unroll
    for (int jj = 0; jj < 11; ++jj) {
        const int j = i - 5 + jj;
        const bool valid = ((unsigned)j < 2048u);
        const int jc = min(max(j, 0), 2047);
        const int gj = (b << 11) + jc;
        const unsigned short* krow = yVp + (size_t)gj * 2048;
        ushortx8 ka = *reinterpret_cast<const ushortx8*>(krow + (lane << 4));
        ushortx8 kb = *reinterpret_cast<const ushortx8*>(krow + (lane << 4) + 8);
        float d = 0.f;
#pragma unroll
        for (int t = 0; t < 8; ++t)
            d += qf[t] * bf2f(ka[t]) + qf[8 + t] * bf2f(kb[t]);
#pragma unroll
        for (int off = 32; off >= 1; off >>= 1) d += __shfl_xor(d, off, 64);
        s[jj] = valid ? (d + r2g + r1[gj]) * 0.03125f : -1e30f;
    }

    float mx = s[0];
#pragma unroll
    for (int jj = 1; jj < 11; ++jj) mx = fmaxf(mx, s[jj]);
    float p[11], sum = 0.f;
#pragma unroll
    for (int jj = 0; jj < 11; ++jj) { p[jj] = expf(s[jj] - mx); sum += p[jj]; }
    const float inv = 1.0f / sum;

    if (lane == 0) {
#pragma unroll
        for (int jj = 0; jj < 11; ++jj) psm[w][jj] = p[jj] * inv;
    }
    __syncthreads();

    const int lo = i - 5;
    float* arow = attn + (size_t)g * 2048;
#pragma unroll
    for (int e = 0; e < 8; ++e) {
        const int c0 = (e << 8) + (lane << 2);
        f32x4 v = (f32x4){0.f, 0.f, 0.f, 0.f};
        if (c0 + 3 >= lo && c0 <= lo + 10) {
#pragma unroll
            for (int t = 0; t < 4; ++t) {
                const int d = c0 + t - lo;
                if ((unsigned)d < 11u) v[t] = psm[w][d];
            }
        }
        *reinterpret_cast<f32x4*>(arow + c0) = v;
    }

    float cacc[16];
#pragma unroll
    for (int t = 0; t < 16; ++t) cacc[t] = 0.f;
#pragma unroll
    for (int jj = 0; jj < 11; ++jj) {
        const int j  = i - 5 + jj;
        const int jc = min(max(j, 0), 2047);
        const float pj = p[jj] * inv;
        const unsigned short* vrow = yVp + ((size_t)((b << 11) + jc)) * 2048 + 1024;
        ushortx8 va = *reinterpret_cast<const ushortx8*>(vrow + (lane << 4));
        ushortx8 vb = *reinterpret_cast<const ushortx8*>(vrow + (lane << 4) + 8);
#pragma unroll
        for (int t = 0; t < 8; ++t) {
            cacc[t]     += pj * bf2f(va[t]);
            cacc[8 + t] += pj * bf2f(vb[t]);
        }
    }
    const int c0 = lane << 4;
    float* op = outp + (size_t)g * 1024 + c0;
#pragma unroll
    for (int q = 0; q < 4; ++q) {
        f32x4 bb = *reinterpret_cast<const f32x4*>(bo + c0 + (q << 2));
        f32x4 o;
#pragma unroll
        for (int t = 0; t < 4; ++t) o[t] = cacc[(q << 2) + t] + bb[t];
        *reinterpret_cast<f32x4*>(op + (q << 2)) = o;
    }
}

// ------------------------------ launch --------------------------------------
extern "C" void kernel_launch(void* const* d_in, const int* in_sizes, int n_in,
                              void* d_out, int out_size, void* d_ws, size_t ws_size,
                              hipStream_t stream) {
    const float* x  = (const float*)d_in[0];
    const float* Wq = (const float*)d_in[1];
    const float* bq = (const float*)d_in[2];
    const float* Wk = (const float*)d_in[3];
    const float* bk = (const float*)d_in[4];
    const float* Wv = (const float*)d_in[5];
    const float* bv = (const float*)d_in[6];
    const float* Wo = (const float*)d_in[7];
    const float* bo = (const float*)d_in[8];

    const size_t MS = 8192, DD = 1024;

    float* out  = (float*)d_out;              // [8192,1024] f32
    float* attn = out + MS * DD;              // [4,2048,2048] f32

    char* ws = (char*)d_ws;
    unsigned short* xh   = (unsigned short*)ws; ws += MS * DD * 2;
    unsigned short* Woh  = (unsigned short*)ws; ws += DD * DD * 2;
    unsigned short* Wqt  = (unsigned short*)ws; ws += DD * DD * 2;
    unsigned short* Wkt  = (unsigned short*)ws; ws += DD * DD * 2;
    unsigned short* Wvt  = (unsigned short*)ws; ws += DD * DD * 2;
    float*          bvo  = (float*)ws;          ws += DD * 4;
    float*          wpart= (float*)ws;          ws += 16 * DD * 4;   // [2][8][1024]
    float*          cbuf = (float*)ws;          ws += 256;
    float*          r1   = (float*)ws;          ws += MS * 4;
    float*          r2   = (float*)ws;          ws += MS * 4;
    float*          part = (float*)ws;          ws += (size_t)8 * DD * DD * 4;
    unsigned short* W2   = (unsigned short*)ws; ws += 2 * DD * DD * 2;
    unsigned short* yVp  = (unsigned short*)ws; ws += MS * 2 * DD * 2;

    // 1) prep: cvt + transpose3 + bvo + w1/w2 partials + c
    prep2<<<dim3(10305), dim3(256), 0, stream>>>(x, Wq, Wk, Wv, Wo, bv, bq, bk,
                                                 xh, Woh, Wqt, Wkt, Wvt, bvo,
                                                 wpart, cbuf);

    // 2) split-K weight GEMM partials + r12 (fence-free)
    splitk_r12<<<dim3(2560), dim3(256), 0, stream>>>(Wqt, Wkt, Woh, Wvt, part,
                                                     xh, wpart, cbuf, r1, r2);

    // 3) reduce partials -> bf16 W2
    reduce_wp<<<dim3(2048), dim3(256), 0, stream>>>(part, W2);

    // 4) [z | Vp] = xh @ W2^T + [0 | bvo]
    gemm_yv<<<dim3(1024), dim3(256), 0, stream>>>(xh, W2, bvo, yVp);

    // 5) band attention: attn rows + final out -> d_out
    attn_band_kernel<<<dim3(2048), dim3(256), 0, stream>>>(xh, yVp, r1, r2, bo,
                                                           attn, out);
}

// Round 15
// 119.097 us; speedup vs baseline: 1.8451x; 1.1684x over previous
//
#include <hip/hip_runtime.h>
#include <hip/hip_bf16.h>
#include <cstdint>
#include <cstddef>

// ---------------------------------------------------------------------------
// LocalAttention: B=4, S=2048, D=1024, WINDOW=10 (|i-j| <= 5)
// Double fold:
//   scores: Q_i.K_j = x_i.z_j + r2_i + r1_j + c,  z = x @ Bwy^T,
//     Bwy = Wqt @ Wkt^T ; w1 = bq@Wk, w2 = bk@Wq, c = bq.bk
//   out = attn @ Vp + bo, Vp = x @ Wp^T + bvo, Wp = Wo@Wv, bvo = Wo@bv
// Pipeline (5 launches, zero duplicated work):
//   prep1   (cvt + transpose3 + bvo)
//   splitk  (Bwy/Wp split-K partials, 512 blocks)
//   redgemv (reduce partials -> W2 || gemv w1/w2 + c)
//   yv_r12  ([z|Vp] = xh @ W2^T + [0|bvo] || r12 rows)
//   attn_band (attn rows + out)
// d_out: out [4,2048,1024] f32, attn [4,2048,2048] f32 (concatenated)
// ---------------------------------------------------------------------------

typedef __attribute__((ext_vector_type(8))) short bf16x8;
typedef __attribute__((ext_vector_type(4))) float f32x4;
typedef __attribute__((ext_vector_type(8))) unsigned short ushortx8;

#define GPTR(x) ((const __attribute__((address_space(1))) void*)(x))
#define LPTR(x) ((__attribute__((address_space(3))) void*)(x))

__device__ __forceinline__ unsigned short f2bf(float f) {
    __hip_bfloat16 h = __float2bfloat16(f);
    unsigned short u;
    __builtin_memcpy(&u, &h, 2);
    return u;
}
__device__ __forceinline__ float bf2f(unsigned short u) {
    unsigned int x = ((unsigned int)u) << 16;
    float f;
    __builtin_memcpy(&f, &x, 4);
    return f;
}

// ------------------- prep1: cvt(x,Wo) | transpose3(Wq,Wk,Wv) | bvo ----------
// blocks [0,9216): cvt ; [9216,9984): transpose ; [9984,10240): bvo
__global__ void prep1(const float* __restrict__ x,  const float* __restrict__ Wq,
                      const float* __restrict__ Wk, const float* __restrict__ Wv,
                      const float* __restrict__ Wo, const float* __restrict__ bv,
                      unsigned short* __restrict__ xh,
                      unsigned short* __restrict__ Woh,
                      unsigned short* __restrict__ Wqt,
                      unsigned short* __restrict__ Wkt,
                      unsigned short* __restrict__ Wvt,
                      float* __restrict__ bvo) {
    __shared__ float tl[64][65];
    const int bid = blockIdx.x;
    if (bid < 9216) {
        const int idx = bid * 256 + threadIdx.x;     // f32x4 units
        const float* src;
        unsigned short* dst;
        int off;
        if (idx < 2097152) { src = x;  dst = xh;  off = idx; }
        else               { src = Wo; dst = Woh; off = idx - 2097152; }
        f32x4 v = reinterpret_cast<const f32x4*>(src)[off];
        ushort4 o;
        o.x = f2bf(v[0]); o.y = f2bf(v[1]); o.z = f2bf(v[2]); o.w = f2bf(v[3]);
        reinterpret_cast<ushort4*>(dst)[off] = o;
    } else if (bid < 9984) {
        const int u   = bid - 9216;                  // 0..767
        const int z   = u >> 8;
        const int rem = u & 255;
        const int by  = rem >> 4;
        const int bx  = rem & 15;
        const float* in = (z == 0) ? Wq : (z == 1) ? Wk : Wv;
        unsigned short* out = (z == 0) ? Wqt : (z == 1) ? Wkt : Wvt;
        const int t  = threadIdx.x;
        const int c  = t & 63;
        const int r4 = t >> 6;
#pragma unroll
        for (int i = 0; i < 16; ++i) {
            const int r = r4 * 16 + i;
            tl[r][c] = in[(size_t)(by * 64 + r) * 1024 + bx * 64 + c];
        }
        __syncthreads();
#pragma unroll
        for (int i = 0; i < 16; ++i) {
            const int r = r4 * 16 + i;
            out[(size_t)(bx * 64 + r) * 1024 + by * 64 + c] = f2bf(tl[c][r]);
        }
    } else {
        const int row  = (bid - 9984) * 4 + (threadIdx.x >> 6);
        const int lane = threadIdx.x & 63;
        float s = 0.f;
#pragma unroll
        for (int k = lane; k < 1024; k += 64)
            s += Wo[(size_t)row * 1024 + k] * bv[k];
#pragma unroll
        for (int off = 32; off >= 1; off >>= 1) s += __shfl_xor(s, off, 64);
        if (lane == 0) bvo[row] = s;
    }
}

// ------------------- GEMM core: 128x128 tile, BK=64, 4 waves (m97) ---------
__device__ __forceinline__ void gemm_core(const unsigned short* __restrict__ A,
                                          const unsigned short* __restrict__ Bw,
                                          int Kstride, int nk, int tm, int tn,
                                          unsigned short* As, unsigned short* Bs,
                                          f32x4 (&acc)[4][4]) {
    const int tid  = threadIdx.x;
    const int lane = tid & 63;
    const int w    = tid >> 6;
    const int wr   = w >> 1;
    const int wc   = w & 1;

    const int lrow8 = lane >> 3;
    const int lcolb = (lane & 7) << 4;

    const char* Abase = (const char*)(A + (size_t)tm * 128 * (size_t)Kstride);
    const char* Bbase = (const char*)(Bw + (size_t)tn * 128 * (size_t)Kstride);
    const size_t rstride = (size_t)Kstride * 2;

    for (int t = 0; t < nk; ++t) {
        const size_t k0b = ((size_t)t << 6) * 2;
#pragma unroll
        for (int ii = 0; ii < 4; ++ii) {
            const int c    = (w << 2) + ii;
            const int row  = (c << 3) + lrow8;
            const int csrc = lcolb ^ ((row & 7) << 4);
            __builtin_amdgcn_global_load_lds(
                GPTR(Abase + (size_t)row * rstride + k0b + (size_t)csrc),
                LPTR((char*)As + (c << 10)), 16, 0, 0);
            __builtin_amdgcn_global_load_lds(
                GPTR(Bbase + (size_t)row * rstride + k0b + (size_t)csrc),
                LPTR((char*)Bs + (c << 10)), 16, 0, 0);
        }
        __syncthreads();

#pragma unroll
        for (int kk = 0; kk < 2; ++kk) {
            bf16x8 af[4], bfr[4];
            const int cb = (kk << 6) + ((lane >> 4) << 4);
#pragma unroll
            for (int m = 0; m < 4; ++m) {
                const int row = (wr << 6) + (m << 4) + (lane & 15);
                af[m] = *reinterpret_cast<const bf16x8*>(
                    (const char*)As + row * 128 + (cb ^ ((row & 7) << 4)));
            }
#pragma unroll
            for (int n = 0; n < 4; ++n) {
                const int row = (wc << 6) + (n << 4) + (lane & 15);
                bfr[n] = *reinterpret_cast<const bf16x8*>(
                    (const char*)Bs + row * 128 + (cb ^ ((row & 7) << 4)));
            }
#pragma unroll
            for (int m = 0; m < 4; ++m)
#pragma unroll
                for (int n = 0; n < 4; ++n)
                    acc[m][n] = __builtin_amdgcn_mfma_f32_16x16x32_bf16(
                        af[m], bfr[n], acc[m][n], 0, 0, 0);
        }
        __syncthreads();
    }
}

// ------------------- splitk: Bwy and Wp partials (512 blocks) ---------------
__launch_bounds__(256, 3)
__global__ void splitk(const unsigned short* __restrict__ Wqt,
                       const unsigned short* __restrict__ Wkt,
                       const unsigned short* __restrict__ Woh,
                       const unsigned short* __restrict__ Wvt,
                       float* __restrict__ part) {
    __shared__ unsigned short As[128 * 64];
    __shared__ unsigned short Bs[128 * 64];
    f32x4 acc[4][4];
#pragma unroll
    for (int m = 0; m < 4; ++m)
#pragma unroll
        for (int n = 0; n < 4; ++n) acc[m][n] = (f32x4){0.f, 0.f, 0.f, 0.f};

    const int bid = blockIdx.x;
    const int mat = bid >> 8;          // 0: Bwy = Wqt@Wkt^T, 1: Wp = Woh@Wvt^T
    const int loc = bid & 255;
    const int ks  = loc >> 6;          // 0..3 -> K offset ks*256
    const int t64 = loc & 63;
    const int tm  = t64 >> 3;
    const int tn  = t64 & 7;

    const unsigned short* A = mat ? Woh : Wqt;
    const unsigned short* B = mat ? Wvt : Wkt;
    gemm_core(A + ks * 256, B + ks * 256, 1024, 4, tm, tn, As, Bs, acc);

    float* dst = part + ((size_t)(mat * 4 + ks) << 20);
    const int lane = threadIdx.x & 63;
    const int w    = threadIdx.x >> 6;
    const int wr   = w >> 1, wc = w & 1;
    const int col0 = (tn << 7) + (wc << 6) + (lane & 15);
    const int row0 = (tm << 7) + (wr << 6) + ((lane >> 4) << 2);
#pragma unroll
    for (int n = 0; n < 4; ++n) {
        const int col = col0 + (n << 4);
#pragma unroll
        for (int m = 0; m < 4; ++m) {
            const int row = row0 + (m << 4);
#pragma unroll
            for (int r = 0; r < 4; ++r)
                dst[(size_t)(row + r) * 1024 + col] = acc[m][n][r];
        }
    }
}

// ------------------- redgemv: reduce partials -> W2 || gemv w1/w2 + c -------
// blocks [0,2048): reduce ; [2048,2304): gemv ; [2304]: c.
__launch_bounds__(256, 4)
__global__ void redgemv(const float* __restrict__ part,
                        unsigned short* __restrict__ W2,
                        const unsigned short* __restrict__ Wqt,
                        const unsigned short* __restrict__ Wkt,
                        const float* __restrict__ bq, const float* __restrict__ bk,
                        float* __restrict__ w1, float* __restrict__ w2,
                        float* __restrict__ cbuf) {
    const int bid = blockIdx.x;
    if (bid < 2048) {
        const int u = bid * 256 + threadIdx.x;   // f32x4 units
        const int mat = u >> 18;
        const int off = u & 262143;
        const f32x4* p = reinterpret_cast<const f32x4*>(part);
        f32x4 s = p[((size_t)(mat * 4 + 0) << 18) + off];
        s += p[((size_t)(mat * 4 + 1) << 18) + off];
        s += p[((size_t)(mat * 4 + 2) << 18) + off];
        s += p[((size_t)(mat * 4 + 3) << 18) + off];
        ushort4 o;
        o.x = f2bf(s[0]); o.y = f2bf(s[1]); o.z = f2bf(s[2]); o.w = f2bf(s[3]);
        reinterpret_cast<ushort4*>(W2)[u] = o;
        return;
    }
    if (bid == 2304) {
        __shared__ float red[256];
        float pc = 0.f;
        for (int n = threadIdx.x; n < 1024; n += 256) pc += bq[n] * bk[n];
        red[threadIdx.x] = pc;
        __syncthreads();
        for (int s = 128; s > 0; s >>= 1) {
            if (threadIdx.x < s) red[threadIdx.x] += red[threadIdx.x + s];
            __syncthreads();
        }
        if (threadIdx.x == 0) cbuf[0] = red[0];
        return;
    }
    // gemv: w1[d] = Wkt[d].bq, w2[d] = Wqt[d].bk
    const int w    = threadIdx.x >> 6;
    const int lane = threadIdx.x & 63;
    const int d    = (bid - 2048) * 4 + w;        // 0..1023
    const int n0   = lane << 4;
    const unsigned short* krow = Wkt + (size_t)d * 1024 + n0;
    const unsigned short* qrow = Wqt + (size_t)d * 1024 + n0;
    ushortx8 ka = *reinterpret_cast<const ushortx8*>(krow);
    ushortx8 kb = *reinterpret_cast<const ushortx8*>(krow + 8);
    ushortx8 qa = *reinterpret_cast<const ushortx8*>(qrow);
    ushortx8 qb = *reinterpret_cast<const ushortx8*>(qrow + 8);
    float a1 = 0.f, a2 = 0.f;
#pragma unroll
    for (int t = 0; t < 8; ++t) {
        a1 += bq[n0 + t] * bf2f(ka[t]) + bq[n0 + 8 + t] * bf2f(kb[t]);
        a2 += bk[n0 + t] * bf2f(qa[t]) + bk[n0 + 8 + t] * bf2f(qb[t]);
    }
#pragma unroll
    for (int off = 32; off >= 1; off >>= 1) {
        a1 += __shfl_xor(a1, off, 64);
        a2 += __shfl_xor(a2, off, 64);
    }
    if (lane == 0) { w1[d] = a1; w2[d] = a2; }
}

// ------------------- yv_r12: gemm_yv (0..1023) || r12 (1024..3071) ----------
// gemm_yv: [z | Vp] = xh @ W2^T + [0 | bvo] -> bf16 [8192,2048]
// r12: r1 = xh@w1 + c, r2 = xh@w2 (direct w1/w2 reads, R11-validated)
__launch_bounds__(256, 4)
__global__ void yv_r12(const unsigned short* __restrict__ A,
                       const unsigned short* __restrict__ Bw,
                       const float* __restrict__ bvo,
                       unsigned short* __restrict__ C,
                       const unsigned short* __restrict__ xh,
                       const float* __restrict__ w1, const float* __restrict__ w2,
                       const float* __restrict__ cbuf,
                       float* __restrict__ r1, float* __restrict__ r2) {
    __shared__ unsigned short As[128 * 64];
    __shared__ unsigned short Bs[128 * 64];
    const int bid = blockIdx.x;
    if (bid >= 1024) {
        const int w    = threadIdx.x >> 6;
        const int lane = threadIdx.x & 63;
        const int g    = (bid - 1024) * 4 + w;
        const unsigned short* row = xh + (size_t)g * 1024 + (lane << 4);
        ushortx8 xa = *reinterpret_cast<const ushortx8*>(row);
        ushortx8 xb = *reinterpret_cast<const ushortx8*>(row + 8);
        float a1 = 0.f, a2 = 0.f;
#pragma unroll
        for (int t = 0; t < 8; ++t) {
            const float xv = bf2f(xa[t]);
            const float xw = bf2f(xb[t]);
            a1 += xv * w1[(lane << 4) + t] + xw * w1[(lane << 4) + 8 + t];
            a2 += xv * w2[(lane << 4) + t] + xw * w2[(lane << 4) + 8 + t];
        }
#pragma unroll
        for (int off = 32; off >= 1; off >>= 1) {
            a1 += __shfl_xor(a1, off, 64);
            a2 += __shfl_xor(a2, off, 64);
        }
        if (lane == 0) { r1[g] = a1 + cbuf[0]; r2[g] = a2; }
        return;
    }

    f32x4 acc[4][4];
#pragma unroll
    for (int m = 0; m < 4; ++m)
#pragma unroll
        for (int n = 0; n < 4; ++n) acc[m][n] = (f32x4){0.f, 0.f, 0.f, 0.f};

    // XCD-chunked swizzle over the 1024 GEMM blocks (literal 1024, not grid)
    const int sid = (bid & 7) * 128 + (bid >> 3);
    const int tm  = sid >> 4;
    const int tn  = sid & 15;

    gemm_core(A, Bw, 1024, 16, tm, tn, As, Bs, acc);

    const int lane = threadIdx.x & 63;
    const int w    = threadIdx.x >> 6;
    const int wr   = w >> 1, wc = w & 1;
    const int seg  = tn >> 3;            // 0: z (no bias), 1: Vp (+bvo)
    const int col0 = (tn << 7) + (wc << 6) + (lane & 15);
    const int row0 = (tm << 7) + (wr << 6) + ((lane >> 4) << 2);
#pragma unroll
    for (int n = 0; n < 4; ++n) {
        const int col = col0 + (n << 4);
        const float bb = seg ? bvo[col & 1023] : 0.f;
#pragma unroll
        for (int m = 0; m < 4; ++m) {
            const int row = row0 + (m << 4);
#pragma unroll
            for (int r = 0; r < 4; ++r)
                C[(size_t)(row + r) * 2048 + col] = f2bf(acc[m][n][r] + bb);
        }
    }
}

// ------------------- band attention: attn rows + final out ------------------
__launch_bounds__(256, 4)
__global__ void attn_band_kernel(const unsigned short* __restrict__ xh,
                                 const unsigned short* __restrict__ yVp,
                                 const float* __restrict__ r1,
                                 const float* __restrict__ r2,
                                 const float* __restrict__ bo,
                                 float* __restrict__ attn,
                                 float* __restrict__ outp) {
    __shared__ float psm[4][16];
    const int bid  = blockIdx.x;
    const int rb   = (bid & 7) * 256 + (bid >> 3);   // XCD-contiguous swizzle
    const int w    = threadIdx.x >> 6;
    const int lane = threadIdx.x & 63;
    const int g    = (rb << 2) + w;                  // row 0..8191
    const int b    = g >> 11;
    const int i    = g & 2047;

    const unsigned short* qrow = xh + (size_t)g * 1024;
    float qf[16];
    {
        ushortx8 qa = *reinterpret_cast<const ushortx8*>(qrow + (lane << 4));
        ushortx8 qb = *reinterpret_cast<const ushortx8*>(qrow + (lane << 4) + 8);
#pragma unroll
        for (int t = 0; t < 8; ++t) { qf[t] = bf2f(qa[t]); qf[8 + t] = bf2f(qb[t]); }
    }
    const float r2g = r2[g];

    float s[11];
#pragma unroll
    for (int jj = 0; jj < 11; ++jj) {
        const int j = i - 5 + jj;
        const bool valid = ((unsigned)j < 2048u);
        const int jc = min(max(j, 0), 2047);
        const int gj = (b << 11) + jc;
        const unsigned short* krow = yVp + (size_t)gj * 2048;
        ushortx8 ka = *reinterpret_cast<const ushortx8*>(krow + (lane << 4));
        ushortx8 kb = *reinterpret_cast<const ushortx8*>(krow + (lane << 4) + 8);
        float d = 0.f;
#pragma unroll
        for (int t = 0; t < 8; ++t)
            d += qf[t] * bf2f(ka[t]) + qf[8 + t] * bf2f(kb[t]);
#pragma unroll
        for (int off = 32; off >= 1; off >>= 1) d += __shfl_xor(d, off, 64);
        s[jj] = valid ? (d + r2g + r1[gj]) * 0.03125f : -1e30f;
    }

    float mx = s[0];
#pragma unroll
    for (int jj = 1; jj < 11; ++jj) mx = fmaxf(mx, s[jj]);
    float p[11], sum = 0.f;
#pragma unroll
    for (int jj = 0; jj < 11; ++jj) { p[jj] = expf(s[jj] - mx); sum += p[jj]; }
    const float inv = 1.0f / sum;

    if (lane == 0) {
#pragma unroll
        for (int jj = 0; jj < 11; ++jj) psm[w][jj] = p[jj] * inv;
    }
    __syncthreads();

    const int lo = i - 5;
    float* arow = attn + (size_t)g * 2048;
#pragma unroll
    for (int e = 0; e < 8; ++e) {
        const int c0 = (e << 8) + (lane << 2);
        f32x4 v = (f32x4){0.f, 0.f, 0.f, 0.f};
        if (c0 + 3 >= lo && c0 <= lo + 10) {
#pragma unroll
            for (int t = 0; t < 4; ++t) {
                const int d = c0 + t - lo;
                if ((unsigned)d < 11u) v[t] = psm[w][d];
            }
        }
        *reinterpret_cast<f32x4*>(arow + c0) = v;
    }

    float cacc[16];
#pragma unroll
    for (int t = 0; t < 16; ++t) cacc[t] = 0.f;
#pragma unroll
    for (int jj = 0; jj < 11; ++jj) {
        const int j  = i - 5 + jj;
        const int jc = min(max(j, 0), 2047);
        const float pj = p[jj] * inv;
        const unsigned short* vrow = yVp + ((size_t)((b << 11) + jc)) * 2048 + 1024;
        ushortx8 va = *reinterpret_cast<const ushortx8*>(vrow + (lane << 4));
        ushortx8 vb = *reinterpret_cast<const ushortx8*>(vrow + (lane << 4) + 8);
#pragma unroll
        for (int t = 0; t < 8; ++t) {
            cacc[t]     += pj * bf2f(va[t]);
            cacc[8 + t] += pj * bf2f(vb[t]);
        }
    }
    const int c0 = lane << 4;
    float* op = outp + (size_t)g * 1024 + c0;
#pragma unroll
    for (int q = 0; q < 4; ++q) {
        f32x4 bb = *reinterpret_cast<const f32x4*>(bo + c0 + (q << 2));
        f32x4 o;
#pragma unroll
        for (int t = 0; t < 4; ++t) o[t] = cacc[(q << 2) + t] + bb[t];
        *reinterpret_cast<f32x4*>(op + (q << 2)) = o;
    }
}

// ------------------------------ launch --------------------------------------
extern "C" void kernel_launch(void* const* d_in, const int* in_sizes, int n_in,
                              void* d_out, int out_size, void* d_ws, size_t ws_size,
                              hipStream_t stream) {
    const float* x  = (const float*)d_in[0];
    const float* Wq = (const float*)d_in[1];
    const float* bq = (const float*)d_in[2];
    const float* Wk = (const float*)d_in[3];
    const float* bk = (const float*)d_in[4];
    const float* Wv = (const float*)d_in[5];
    const float* bv = (const float*)d_in[6];
    const float* Wo = (const float*)d_in[7];
    const float* bo = (const float*)d_in[8];

    const size_t MS = 8192, DD = 1024;

    float* out  = (float*)d_out;              // [8192,1024] f32
    float* attn = out + MS * DD;              // [4,2048,2048] f32

    char* ws = (char*)d_ws;
    unsigned short* xh   = (unsigned short*)ws; ws += MS * DD * 2;
    unsigned short* Woh  = (unsigned short*)ws; ws += DD * DD * 2;
    unsigned short* Wqt  = (unsigned short*)ws; ws += DD * DD * 2;
    unsigned short* Wkt  = (unsigned short*)ws; ws += DD * DD * 2;
    unsigned short* Wvt  = (unsigned short*)ws; ws += DD * DD * 2;
    float*          bvo  = (float*)ws;          ws += DD * 4;
    float*          w1   = (float*)ws;          ws += DD * 4;
    float*          w2   = (float*)ws;          ws += DD * 4;
    float*          cbuf = (float*)ws;          ws += 256;
    float*          r1   = (float*)ws;          ws += MS * 4;
    float*          r2   = (float*)ws;          ws += MS * 4;
    float*          part = (float*)ws;          ws += (size_t)8 * DD * DD * 4;
    unsigned short* W2   = (unsigned short*)ws; ws += 2 * DD * DD * 2;
    unsigned short* yVp  = (unsigned short*)ws; ws += MS * 2 * DD * 2;

    // 1) prep: cvt + transpose3 + bvo
    prep1<<<dim3(10240), dim3(256), 0, stream>>>(x, Wq, Wk, Wv, Wo, bv,
                                                 xh, Woh, Wqt, Wkt, Wvt, bvo);

    // 2) split-K weight GEMM partials
    splitk<<<dim3(512), dim3(256), 0, stream>>>(Wqt, Wkt, Woh, Wvt, part);

    // 3) reduce partials -> W2 || gemv w1/w2 + c
    redgemv<<<dim3(2305), dim3(256), 0, stream>>>(part, W2, Wqt, Wkt, bq, bk,
                                                  w1, w2, cbuf);

    // 4) [z | Vp] GEMM || r12 rows
    yv_r12<<<dim3(3072), dim3(256), 0, stream>>>(xh, W2, bvo, yVp,
                                                 xh, w1, w2, cbuf, r1, r2);

    // 5) band attention: attn rows + final out -> d_out
    attn_band_kernel<<<dim3(2048), dim3(256), 0, stream>>>(xh, yVp, r1, r2, bo,
                                                           attn, out);
}

// Round 16
// 117.019 us; speedup vs baseline: 1.8779x; 1.0178x over previous
//
#include <hip/hip_runtime.h>
#include <hip/hip_bf16.h>
#include <cstdint>
#include <cstddef>

// ---------------------------------------------------------------------------
// LocalAttention: B=4, S=2048, D=1024, WINDOW=10 (|i-j| <= 5)
// Double fold:
//   scores: Q_i.K_j = x_i.z_j + r2_i + r1_j + c,  z = x @ Bwy^T,
//     Bwy = Wqt @ Wkt^T ; w1 = bq@Wk, w2 = bk@Wq, c = bq.bk
//   out = attn @ Vp + bo, Vp = x @ Wp^T + bvo, Wp = Wo@Wv, bvo = Wo@bv
// Pipeline (5 launches, HBM work packed under compute):
//   prepW   (transpose3 + Wo-cvt)                      [splitk's inputs only]
//   skx     (splitk MFMA || x-cvt || bvo || gemv w1/w2 || c)
//   reduce_wp (partials -> bf16 W2)
//   yv_r12  ([z|Vp] = xh @ W2^T + [0|bvo] || r12 rows)
//   attn_band (attn rows + out)
// d_out: out [4,2048,1024] f32, attn [4,2048,2048] f32 (concatenated)
// ---------------------------------------------------------------------------

typedef __attribute__((ext_vector_type(8))) short bf16x8;
typedef __attribute__((ext_vector_type(4))) float f32x4;
typedef __attribute__((ext_vector_type(8))) unsigned short ushortx8;

#define GPTR(x) ((const __attribute__((address_space(1))) void*)(x))
#define LPTR(x) ((__attribute__((address_space(3))) void*)(x))

__device__ __forceinline__ unsigned short f2bf(float f) {
    __hip_bfloat16 h = __float2bfloat16(f);
    unsigned short u;
    __builtin_memcpy(&u, &h, 2);
    return u;
}
__device__ __forceinline__ float bf2f(unsigned short u) {
    unsigned int x = ((unsigned int)u) << 16;
    float f;
    __builtin_memcpy(&f, &x, 4);
    return f;
}

// ------------------- prepW: transpose3(Wq,Wk,Wv) | cvt(Wo) ------------------
// blocks [0,768): transpose ; [768,1792): Wo cvt
__global__ void prepW(const float* __restrict__ Wq, const float* __restrict__ Wk,
                      const float* __restrict__ Wv, const float* __restrict__ Wo,
                      unsigned short* __restrict__ Wqt,
                      unsigned short* __restrict__ Wkt,
                      unsigned short* __restrict__ Wvt,
                      unsigned short* __restrict__ Woh) {
    __shared__ float tl[64][65];
    const int bid = blockIdx.x;
    if (bid < 768) {
        const int z   = bid >> 8;
        const int rem = bid & 255;
        const int by  = rem >> 4;
        const int bx  = rem & 15;
        const float* in = (z == 0) ? Wq : (z == 1) ? Wk : Wv;
        unsigned short* out = (z == 0) ? Wqt : (z == 1) ? Wkt : Wvt;
        const int t  = threadIdx.x;
        const int c  = t & 63;
        const int r4 = t >> 6;
#pragma unroll
        for (int i = 0; i < 16; ++i) {
            const int r = r4 * 16 + i;
            tl[r][c] = in[(size_t)(by * 64 + r) * 1024 + bx * 64 + c];
        }
        __syncthreads();
#pragma unroll
        for (int i = 0; i < 16; ++i) {
            const int r = r4 * 16 + i;
            out[(size_t)(bx * 64 + r) * 1024 + by * 64 + c] = f2bf(tl[c][r]);
        }
    } else {
        const int off = (bid - 768) * 256 + threadIdx.x;   // f32x4 units of Wo
        f32x4 v = reinterpret_cast<const f32x4*>(Wo)[off];
        ushort4 o;
        o.x = f2bf(v[0]); o.y = f2bf(v[1]); o.z = f2bf(v[2]); o.w = f2bf(v[3]);
        reinterpret_cast<ushort4*>(Woh)[off] = o;
    }
}

// ------------------- GEMM core: 128x128 tile, BK=64, 4 waves (m97) ---------
__device__ __forceinline__ void gemm_core(const unsigned short* __restrict__ A,
                                          const unsigned short* __restrict__ Bw,
                                          int Kstride, int nk, int tm, int tn,
                                          unsigned short* As, unsigned short* Bs,
                                          f32x4 (&acc)[4][4]) {
    const int tid  = threadIdx.x;
    const int lane = tid & 63;
    const int w    = tid >> 6;
    const int wr   = w >> 1;
    const int wc   = w & 1;

    const int lrow8 = lane >> 3;
    const int lcolb = (lane & 7) << 4;

    const char* Abase = (const char*)(A + (size_t)tm * 128 * (size_t)Kstride);
    const char* Bbase = (const char*)(Bw + (size_t)tn * 128 * (size_t)Kstride);
    const size_t rstride = (size_t)Kstride * 2;

    for (int t = 0; t < nk; ++t) {
        const size_t k0b = ((size_t)t << 6) * 2;
#pragma unroll
        for (int ii = 0; ii < 4; ++ii) {
            const int c    = (w << 2) + ii;
            const int row  = (c << 3) + lrow8;
            const int csrc = lcolb ^ ((row & 7) << 4);
            __builtin_amdgcn_global_load_lds(
                GPTR(Abase + (size_t)row * rstride + k0b + (size_t)csrc),
                LPTR((char*)As + (c << 10)), 16, 0, 0);
            __builtin_amdgcn_global_load_lds(
                GPTR(Bbase + (size_t)row * rstride + k0b + (size_t)csrc),
                LPTR((char*)Bs + (c << 10)), 16, 0, 0);
        }
        __syncthreads();

#pragma unroll
        for (int kk = 0; kk < 2; ++kk) {
            bf16x8 af[4], bfr[4];
            const int cb = (kk << 6) + ((lane >> 4) << 4);
#pragma unroll
            for (int m = 0; m < 4; ++m) {
                const int row = (wr << 6) + (m << 4) + (lane & 15);
                af[m] = *reinterpret_cast<const bf16x8*>(
                    (const char*)As + row * 128 + (cb ^ ((row & 7) << 4)));
            }
#pragma unroll
            for (int n = 0; n < 4; ++n) {
                const int row = (wc << 6) + (n << 4) + (lane & 15);
                bfr[n] = *reinterpret_cast<const bf16x8*>(
                    (const char*)Bs + row * 128 + (cb ^ ((row & 7) << 4)));
            }
#pragma unroll
            for (int m = 0; m < 4; ++m)
#pragma unroll
                for (int n = 0; n < 4; ++n)
                    acc[m][n] = __builtin_amdgcn_mfma_f32_16x16x32_bf16(
                        af[m], bfr[n], acc[m][n], 0, 0, 0);
        }
        __syncthreads();
    }
}

// ------------------- skx: splitk | cvt-x | bvo | gemv w1/w2 | c -------------
// bids [0,512): split-K partials (first: MFMA starts while rest streams HBM)
// [512,8704): x cvt ; [8704,8960): bvo ; [8960,9216): gemv ; [9216]: c.
__launch_bounds__(256, 3)
__global__ void skx(const unsigned short* __restrict__ Wqt,
                    const unsigned short* __restrict__ Wkt,
                    const unsigned short* __restrict__ Woh,
                    const unsigned short* __restrict__ Wvt,
                    float* __restrict__ part,
                    const float* __restrict__ x, unsigned short* __restrict__ xh,
                    const float* __restrict__ Wo, const float* __restrict__ bv,
                    float* __restrict__ bvo,
                    const float* __restrict__ bq, const float* __restrict__ bk,
                    float* __restrict__ w1, float* __restrict__ w2,
                    float* __restrict__ cbuf) {
    __shared__ unsigned short As[128 * 64];
    __shared__ unsigned short Bs[128 * 64];
    const int bid = blockIdx.x;
    if (bid >= 512) {
        if (bid < 8704) {
            // ---- x f32 -> bf16 ----
            const int off = (bid - 512) * 256 + threadIdx.x;   // f32x4 units
            f32x4 v = reinterpret_cast<const f32x4*>(x)[off];
            ushort4 o;
            o.x = f2bf(v[0]); o.y = f2bf(v[1]); o.z = f2bf(v[2]); o.w = f2bf(v[3]);
            reinterpret_cast<ushort4*>(xh)[off] = o;
        } else if (bid < 8960) {
            // ---- bvo = Wo @ bv ----
            const int row  = (bid - 8704) * 4 + (threadIdx.x >> 6);
            const int lane = threadIdx.x & 63;
            float s = 0.f;
#pragma unroll
            for (int k = lane; k < 1024; k += 64)
                s += Wo[(size_t)row * 1024 + k] * bv[k];
#pragma unroll
            for (int off = 32; off >= 1; off >>= 1) s += __shfl_xor(s, off, 64);
            if (lane == 0) bvo[row] = s;
        } else if (bid < 9216) {
            // ---- gemv: w1[d] = Wkt[d].bq, w2[d] = Wqt[d].bk ----
            const int w    = threadIdx.x >> 6;
            const int lane = threadIdx.x & 63;
            const int d    = (bid - 8960) * 4 + w;
            const int n0   = lane << 4;
            const unsigned short* krow = Wkt + (size_t)d * 1024 + n0;
            const unsigned short* qrow = Wqt + (size_t)d * 1024 + n0;
            ushortx8 ka = *reinterpret_cast<const ushortx8*>(krow);
            ushortx8 kb = *reinterpret_cast<const ushortx8*>(krow + 8);
            ushortx8 qa = *reinterpret_cast<const ushortx8*>(qrow);
            ushortx8 qb = *reinterpret_cast<const ushortx8*>(qrow + 8);
            float a1 = 0.f, a2 = 0.f;
#pragma unroll
            for (int t = 0; t < 8; ++t) {
                a1 += bq[n0 + t] * bf2f(ka[t]) + bq[n0 + 8 + t] * bf2f(kb[t]);
                a2 += bk[n0 + t] * bf2f(qa[t]) + bk[n0 + 8 + t] * bf2f(qb[t]);
            }
#pragma unroll
            for (int off = 32; off >= 1; off >>= 1) {
                a1 += __shfl_xor(a1, off, 64);
                a2 += __shfl_xor(a2, off, 64);
            }
            if (lane == 0) { w1[d] = a1; w2[d] = a2; }
        } else {
            // ---- c = bq.bk ----
            __shared__ float red[256];
            float pc = 0.f;
            for (int n = threadIdx.x; n < 1024; n += 256) pc += bq[n] * bk[n];
            red[threadIdx.x] = pc;
            __syncthreads();
            for (int s = 128; s > 0; s >>= 1) {
                if (threadIdx.x < s) red[threadIdx.x] += red[threadIdx.x + s];
                __syncthreads();
            }
            if (threadIdx.x == 0) cbuf[0] = red[0];
        }
        return;
    }

    // ---- split-K weight GEMM partials ----
    f32x4 acc[4][4];
#pragma unroll
    for (int m = 0; m < 4; ++m)
#pragma unroll
        for (int n = 0; n < 4; ++n) acc[m][n] = (f32x4){0.f, 0.f, 0.f, 0.f};

    const int mat = bid >> 8;          // 0: Bwy = Wqt@Wkt^T, 1: Wp = Woh@Wvt^T
    const int loc = bid & 255;
    const int ks  = loc >> 6;          // 0..3 -> K offset ks*256
    const int t64 = loc & 63;
    const int tm  = t64 >> 3;
    const int tn  = t64 & 7;

    const unsigned short* A = mat ? Woh : Wqt;
    const unsigned short* B = mat ? Wvt : Wkt;
    gemm_core(A + ks * 256, B + ks * 256, 1024, 4, tm, tn, As, Bs, acc);

    float* dst = part + ((size_t)(mat * 4 + ks) << 20);
    const int lane = threadIdx.x & 63;
    const int w    = threadIdx.x >> 6;
    const int wr   = w >> 1, wc = w & 1;
    const int col0 = (tn << 7) + (wc << 6) + (lane & 15);
    const int row0 = (tm << 7) + (wr << 6) + ((lane >> 4) << 2);
#pragma unroll
    for (int n = 0; n < 4; ++n) {
        const int col = col0 + (n << 4);
#pragma unroll
        for (int m = 0; m < 4; ++m) {
            const int row = row0 + (m << 4);
#pragma unroll
            for (int r = 0; r < 4; ++r)
                dst[(size_t)(row + r) * 1024 + col] = acc[m][n][r];
        }
    }
}

// ------------------- reduce partials -> W2 = [Bwy; Wp] bf16 [2048][1024] ----
__global__ void reduce_wp(const float* __restrict__ part,
                          unsigned short* __restrict__ W2) {
    const int u = blockIdx.x * 256 + threadIdx.x;   // f32x4 units
    const int mat = u >> 18;
    const int off = u & 262143;
    const f32x4* p = reinterpret_cast<const f32x4*>(part);
    f32x4 s = p[((size_t)(mat * 4 + 0) << 18) + off];
    s += p[((size_t)(mat * 4 + 1) << 18) + off];
    s += p[((size_t)(mat * 4 + 2) << 18) + off];
    s += p[((size_t)(mat * 4 + 3) << 18) + off];
    ushort4 o;
    o.x = f2bf(s[0]); o.y = f2bf(s[1]); o.z = f2bf(s[2]); o.w = f2bf(s[3]);
    reinterpret_cast<ushort4*>(W2)[u] = o;
}

// ------------------- yv_r12: gemm_yv (0..1023) || r12 (1024..3071) ----------
__launch_bounds__(256, 4)
__global__ void yv_r12(const unsigned short* __restrict__ A,
                       const unsigned short* __restrict__ Bw,
                       const float* __restrict__ bvo,
                       unsigned short* __restrict__ C,
                       const unsigned short* __restrict__ xh,
                       const float* __restrict__ w1, const float* __restrict__ w2,
                       const float* __restrict__ cbuf,
                       float* __restrict__ r1, float* __restrict__ r2) {
    __shared__ unsigned short As[128 * 64];
    __shared__ unsigned short Bs[128 * 64];
    const int bid = blockIdx.x;
    if (bid >= 1024) {
        const int w    = threadIdx.x >> 6;
        const int lane = threadIdx.x & 63;
        const int g    = (bid - 1024) * 4 + w;
        const unsigned short* row = xh + (size_t)g * 1024 + (lane << 4);
        ushortx8 xa = *reinterpret_cast<const ushortx8*>(row);
        ushortx8 xb = *reinterpret_cast<const ushortx8*>(row + 8);
        float a1 = 0.f, a2 = 0.f;
#pragma unroll
        for (int t = 0; t < 8; ++t) {
            const float xv = bf2f(xa[t]);
            const float xw = bf2f(xb[t]);
            a1 += xv * w1[(lane << 4) + t] + xw * w1[(lane << 4) + 8 + t];
            a2 += xv * w2[(lane << 4) + t] + xw * w2[(lane << 4) + 8 + t];
        }
#pragma unroll
        for (int off = 32; off >= 1; off >>= 1) {
            a1 += __shfl_xor(a1, off, 64);
            a2 += __shfl_xor(a2, off, 64);
        }
        if (lane == 0) { r1[g] = a1 + cbuf[0]; r2[g] = a2; }
        return;
    }

    f32x4 acc[4][4];
#pragma unroll
    for (int m = 0; m < 4; ++m)
#pragma unroll
        for (int n = 0; n < 4; ++n) acc[m][n] = (f32x4){0.f, 0.f, 0.f, 0.f};

    // XCD-chunked swizzle over the 1024 GEMM blocks (literal 1024)
    const int sid = (bid & 7) * 128 + (bid >> 3);
    const int tm  = sid >> 4;
    const int tn  = sid & 15;

    gemm_core(A, Bw, 1024, 16, tm, tn, As, Bs, acc);

    const int lane = threadIdx.x & 63;
    const int w    = threadIdx.x >> 6;
    const int wr   = w >> 1, wc = w & 1;
    const int seg  = tn >> 3;            // 0: z (no bias), 1: Vp (+bvo)
    const int col0 = (tn << 7) + (wc << 6) + (lane & 15);
    const int row0 = (tm << 7) + (wr << 6) + ((lane >> 4) << 2);
#pragma unroll
    for (int n = 0; n < 4; ++n) {
        const int col = col0 + (n << 4);
        const float bb = seg ? bvo[col & 1023] : 0.f;
#pragma unroll
        for (int m = 0; m < 4; ++m) {
            const int row = row0 + (m << 4);
#pragma unroll
            for (int r = 0; r < 4; ++r)
                C[(size_t)(row + r) * 2048 + col] = f2bf(acc[m][n][r] + bb);
        }
    }
}

// ------------------- band attention: attn rows + final out ------------------
__launch_bounds__(256, 4)
__global__ void attn_band_kernel(const unsigned short* __restrict__ xh,
                                 const unsigned short* __restrict__ yVp,
                                 const float* __restrict__ r1,
                                 const float* __restrict__ r2,
                                 const float* __restrict__ bo,
                                 float* __restrict__ attn,
                                 float* __restrict__ outp) {
    __shared__ float psm[4][16];
    const int bid  = blockIdx.x;
    const int rb   = (bid & 7) * 256 + (bid >> 3);   // XCD-contiguous swizzle
    const int w    = threadIdx.x >> 6;
    const int lane = threadIdx.x & 63;
    const int g    = (rb << 2) + w;                  // row 0..8191
    const int b    = g >> 11;
    const int i    = g & 2047;

    const unsigned short* qrow = xh + (size_t)g * 1024;
    float qf[16];
    {
        ushortx8 qa = *reinterpret_cast<const ushortx8*>(qrow + (lane << 4));
        ushortx8 qb = *reinterpret_cast<const ushortx8*>(qrow + (lane << 4) + 8);
#pragma unroll
        for (int t = 0; t < 8; ++t) { qf[t] = bf2f(qa[t]); qf[8 + t] = bf2f(qb[t]); }
    }
    const float r2g = r2[g];

    float s[11];
#pragma unroll
    for (int jj = 0; jj < 11; ++jj) {
        const int j = i - 5 + jj;
        const bool valid = ((unsigned)j < 2048u);
        const int jc = min(max(j, 0), 2047);
        const int gj = (b << 11) + jc;
        const unsigned short* krow = yVp + (size_t)gj * 2048;
        ushortx8 ka = *reinterpret_cast<const ushortx8*>(krow + (lane << 4));
        ushortx8 kb = *reinterpret_cast<const ushortx8*>(krow + (lane << 4) + 8);
        float d = 0.f;
#pragma unroll
        for (int t = 0; t < 8; ++t)
            d += qf[t] * bf2f(ka[t]) + qf[8 + t] * bf2f(kb[t]);
#pragma unroll
        for (int off = 32; off >= 1; off >>= 1) d += __shfl_xor(d, off, 64);
        s[jj] = valid ? (d + r2g + r1[gj]) * 0.03125f : -1e30f;
    }

    float mx = s[0];
#pragma unroll
    for (int jj = 1; jj < 11; ++jj) mx = fmaxf(mx, s[jj]);
    float p[11], sum = 0.f;
#pragma unroll
    for (int jj = 0; jj < 11; ++jj) { p[jj] = expf(s[jj] - mx); sum += p[jj]; }
    const float inv = 1.0f / sum;

    if (lane == 0) {
#pragma unroll
        for (int jj = 0; jj < 11; ++jj) psm[w][jj] = p[jj] * inv;
    }
    __syncthreads();

    const int lo = i - 5;
    float* arow = attn + (size_t)g * 2048;
#pragma unroll
    for (int e = 0; e < 8; ++e) {
        const int c0 = (e << 8) + (lane << 2);
        f32x4 v = (f32x4){0.f, 0.f, 0.f, 0.f};
        if (c0 + 3 >= lo && c0 <= lo + 10) {
#pragma unroll
            for (int t = 0; t < 4; ++t) {
                const int d = c0 + t - lo;
                if ((unsigned)d < 11u) v[t] = psm[w][d];
            }
        }
        *reinterpret_cast<f32x4*>(arow + c0) = v;
    }

    float cacc[16];
#pragma unroll
    for (int t = 0; t < 16; ++t) cacc[t] = 0.f;
#pragma unroll
    for (int jj = 0; jj < 11; ++jj) {
        const int j  = i - 5 + jj;
        const int jc = min(max(j, 0), 2047);
        const float pj = p[jj] * inv;
        const unsigned short* vrow = yVp + ((size_t)((b << 11) + jc)) * 2048 + 1024;
        ushortx8 va = *reinterpret_cast<const ushortx8*>(vrow + (lane << 4));
        ushortx8 vb = *reinterpret_cast<const ushortx8*>(vrow + (lane << 4) + 8);
#pragma unroll
        for (int t = 0; t < 8; ++t) {
            cacc[t]     += pj * bf2f(va[t]);
            cacc[8 + t] += pj * bf2f(vb[t]);
        }
    }
    const int c0 = lane << 4;
    float* op = outp + (size_t)g * 1024 + c0;
#pragma unroll
    for (int q = 0; q < 4; ++q) {
        f32x4 bb = *reinterpret_cast<const f32x4*>(bo + c0 + (q << 2));
        f32x4 o;
#pragma unroll
        for (int t = 0; t < 4; ++t) o[t] = cacc[(q << 2) + t] + bb[t];
        *reinterpret_cast<f32x4*>(op + (q << 2)) = o;
    }
}

// ------------------------------ launch --------------------------------------
extern "C" void kernel_launch(void* const* d_in, const int* in_sizes, int n_in,
                              void* d_out, int out_size, void* d_ws, size_t ws_size,
                              hipStream_t stream) {
    const float* x  = (const float*)d_in[0];
    const float* Wq = (const float*)d_in[1];
    const float* bq = (const float*)d_in[2];
    const float* Wk = (const float*)d_in[3];
    const float* bk = (const float*)d_in[4];
    const float* Wv = (const float*)d_in[5];
    const float* bv = (const float*)d_in[6];
    const float* Wo = (const float*)d_in[7];
    const float* bo = (const float*)d_in[8];

    const size_t MS = 8192, DD = 1024;

    float* out  = (float*)d_out;              // [8192,1024] f32
    float* attn = out + MS * DD;              // [4,2048,2048] f32

    char* ws = (char*)d_ws;
    unsigned short* xh   = (unsigned short*)ws; ws += MS * DD * 2;
    unsigned short* Woh  = (unsigned short*)ws; ws += DD * DD * 2;
    unsigned short* Wqt  = (unsigned short*)ws; ws += DD * DD * 2;
    unsigned short* Wkt  = (unsigned short*)ws; ws += DD * DD * 2;
    unsigned short* Wvt  = (unsigned short*)ws; ws += DD * DD * 2;
    float*          bvo  = (float*)ws;          ws += DD * 4;
    float*          w1   = (float*)ws;          ws += DD * 4;
    float*          w2   = (float*)ws;          ws += DD * 4;
    float*          cbuf = (float*)ws;          ws += 256;
    float*          r1   = (float*)ws;          ws += MS * 4;
    float*          r2   = (float*)ws;          ws += MS * 4;
    float*          part = (float*)ws;          ws += (size_t)8 * DD * DD * 4;
    unsigned short* W2   = (unsigned short*)ws; ws += 2 * DD * DD * 2;
    unsigned short* yVp  = (unsigned short*)ws; ws += MS * 2 * DD * 2;

    // 1) weights prep: transposes + Wo cvt (exactly what splitk needs)
    prepW<<<dim3(1792), dim3(256), 0, stream>>>(Wq, Wk, Wv, Wo,
                                                Wqt, Wkt, Wvt, Woh);

    // 2) splitk MFMA || x-cvt || bvo || gemv w1/w2 || c  (HBM hides under MFMA)
    skx<<<dim3(9217), dim3(256), 0, stream>>>(Wqt, Wkt, Woh, Wvt, part,
                                              x, xh, Wo, bv, bvo,
                                              bq, bk, w1, w2, cbuf);

    // 3) reduce partials -> bf16 W2
    reduce_wp<<<dim3(2048), dim3(256), 0, stream>>>(part, W2);

    // 4) [z | Vp] GEMM || r12 rows
    yv_r12<<<dim3(3072), dim3(256), 0, stream>>>(xh, W2, bvo, yVp,
                                                 xh, w1, w2, cbuf, r1, r2);

    // 5) band attention: attn rows + final out -> d_out
    attn_band_kernel<<<dim3(2048), dim3(256), 0, stream>>>(xh, yVp, r1, r2, bo,
                                                           attn, out);
}